// Round 3
// baseline (657.127 us; speedup 1.0000x reference)
//
#include <hip/hip_runtime.h>
#include <math.h>

#define N   4096
#define NO  4097   // output spatial dim (4096 + 4pad - 4 + 1)
#define TO  32     // output tile
#define GW  129    // grid width = ceil(NO/TO)

struct OrientCoef { float c[8]; float s[8]; };

// LDS 10,664 B. min 6 blocks/CU guaranteed (VGPR <= 85); 8 if alloc fits 64.
__global__ __launch_bounds__(256, 6) void sift_fused(const float* __restrict__ x,
                                                     float* __restrict__ out,
                                                     OrientCoef cf) {
    // ---- bijective XCD-aware swizzle: consecutive tiles -> same XCD L2 ----
    int bid = blockIdx.y * GW + blockIdx.x;
    {
        const int nwg = GW * GW;             // 16641
        const int q = nwg / 8, r = nwg % 8;  // 2080, 1
        int xcd = bid & 7, local = bid >> 3;
        bid = (xcd < r ? xcd * (q + 1) : r * (q + 1) + (xcd - r) * q) + local;
    }
    const int i0  = (bid / GW) * TO;
    const int j0  = (bid % GW) * TO;
    const int tid = threadIdx.x;

    __shared__ float xs[37][38];       // input halo (+1 pad col)
    __shared__ float packed[35][36];   // (mag | idx) packed f32 (+1 pad col)

    // ---- phase 1: stage x halo (zero-padded) ----
    for (int l = tid; l < 37 * 37; l += 256) {
        int lr = l / 37, lc = l % 37;
        int gr = i0 - 3 + lr, gc = j0 - 3 + lc;
        float v = 0.0f;
        if (gr >= 0 && gr < N && gc >= 0 && gc < N) v = x[(size_t)gr * N + gc];
        xs[lr][lc] = v;
    }
    __syncthreads();

    // ---- phase 2: Sobel + magnitude + orientation argmax, pack (mag|idx) ----
    for (int l = tid; l < 35 * 35; l += 256) {
        int lr = l / 35, lc = l % 35;
        int gr = i0 - 2 + lr, gc = j0 - 2 + lc;
        float pv = 0.0f;
        if (gr >= 0 && gr < N && gc >= 0 && gc < N) {
            float x00 = xs[lr][lc],     x01 = xs[lr][lc + 1],     x02 = xs[lr][lc + 2];
            float x10 = xs[lr + 1][lc],                           x12 = xs[lr + 1][lc + 2];
            float x20 = xs[lr + 2][lc], x21 = xs[lr + 2][lc + 1], x22 = xs[lr + 2][lc + 2];
            // unflipped sobel taps (lax conv = cross-correlation)
            float dx = (x02 - x00) + 2.0f * (x12 - x10) + (x22 - x20);
            float dy = (x20 - x00) + 2.0f * (x21 - x01) + (x22 - x02);
            float mag = sqrtf(dx * dx + dy * dy);
            // per-bin coefficients (reference rounds each f32 angle separately)
            int best = 0;
            float bv = fmaf(cf.s[0], dy, cf.c[0] * dx);
            #pragma unroll
            for (int o = 1; o < 8; ++o) {
                float cs = fmaf(cf.s[o], dy, cf.c[o] * dx);
                if (cs > bv) { bv = cs; best = o; }
            }
            // pack idx into low 3 mantissa bits (<= 8e-7 relative mag error)
            pv = __uint_as_float((__float_as_uint(mag) & ~7u) | (unsigned)best);
        }
        packed[lr][lc] = pv;
    }
    __syncthreads();

    // ---- phase 3: thread <-> (row-group, column). Each input value read ONCE;
    //      all 8 channel sums kept in registers (no 8x channel-wave redundancy).
    //      Lanes read stride-1 cols; the two row-group halves of a wave are
    //      offset by 4*36 words = bank+16 -> 2-way conflict (free, m136).
    {
        const int rg = tid >> 5;            // 0..7 : 4-output-row group
        const int jt = tid & 31;            // 0..31: column
        const int j  = j0 + jt;
        const bool jok = (j < NO);
        const int rbase = rg * 4;           // first input row of this group

        float w0[8], w1[8], w2[8];          // rolling h-vectors (rows r-3..r-1)
        #pragma unroll
        for (int rr = 0; rr < 7; ++rr) {    // input rows rbase..rbase+6
            const int r = rbase + rr;
            float m0 = packed[r][jt],     m1 = packed[r][jt + 1];
            float m2 = packed[r][jt + 2], m3 = packed[r][jt + 3];
            unsigned b0 = __float_as_uint(m0) & 7u, b1 = __float_as_uint(m1) & 7u;
            unsigned b2 = __float_as_uint(m2) & 7u, b3 = __float_as_uint(m3) & 7u;
            float h[8];
            #pragma unroll
            for (int o = 0; o < 8; ++o) {
                unsigned uo = (unsigned)o;
                float s = (b0 == uo) ? m0 : 0.0f;
                s += (b1 == uo) ? m1 : 0.0f;
                s += (b2 == uo) ? m2 : 0.0f;
                s += (b3 == uo) ? m3 : 0.0f;
                h[o] = s;
            }
            if (rr >= 3) {                  // compile-time after unroll
                int i = i0 + rbase + rr - 3;
                if (jok && i < NO) {
                    #pragma unroll
                    for (int o = 0; o < 8; ++o)
                        out[((size_t)o * NO + i) * NO + j] =
                            (w0[o] + w1[o]) + (w2[o] + h[o]);
                }
            }
            #pragma unroll
            for (int o = 0; o < 8; ++o) { w0[o] = w1[o]; w1[o] = w2[o]; w2[o] = h[o]; }
        }
    }
}

extern "C" void kernel_launch(void* const* d_in, const int* in_sizes, int n_in,
                              void* d_out, int out_size, void* d_ws, size_t ws_size,
                              hipStream_t stream) {
    const float* x = (const float*)d_in[0];
    float* out = (float*)d_out;

    // Emulate reference coefficient pipeline exactly:
    //   angle_o = f32( f32(2o+1) * f32(pi/8) ); coeff = f32(cos/sin(angle_o))
    OrientCoef cf;
    const float pi8 = (float)(M_PI / 8.0);   // fp32(pi/8)
    for (int o = 0; o < 8; ++o) {
        float angle = (float)(2 * o + 1) * pi8;          // f32 multiply
        cf.c[o] = (float)cos((double)angle);             // correctly-rounded f32
        cf.s[o] = (float)sin((double)angle);
    }

    dim3 grid(GW, GW);   // 129 x 129
    sift_fused<<<grid, dim3(256), 0, stream>>>(x, out, cf);
}